// Round 6
// baseline (288.222 us; speedup 1.0000x reference)
//
#include <hip/hip_runtime.h>
#include <hip/hip_bf16.h>

#define BB 2
#define SS 2048
#define DD 1024
#define HH 16
#define HD 64

typedef __attribute__((ext_vector_type(8))) short bf16x8;
typedef __attribute__((ext_vector_type(4))) float floatx4;

__device__ __forceinline__ short f2bf(float x) {
  __hip_bfloat16 h = __float2bfloat16(x);
  return __builtin_bit_cast(short, h);
}

// async global->LDS, 16B per lane; LDS dest is wave-uniform base + lane*16
__device__ __forceinline__ void load_lds16(const void* g, void* l) {
  __builtin_amdgcn_global_load_lds(
      (const __attribute__((address_space(1))) unsigned int*)g,
      (__attribute__((address_space(3))) unsigned int*)l, 16, 0, 0);
}

__device__ __forceinline__ float redsum16(float v) {
  v += __shfl_xor(v, 1, 64);
  v += __shfl_xor(v, 2, 64);
  v += __shfl_xor(v, 4, 64);
  v += __shfl_xor(v, 8, 64);
  return v;
}

// ---------------------------------------------------------------------------
// fp32 -> bf16 element-wise for q,k,v. grid (4096,1,3), block 256.
// ---------------------------------------------------------------------------
__global__ __launch_bounds__(256) void conv_in(
    const float* __restrict__ q, const float* __restrict__ k,
    const float* __restrict__ v, short* __restrict__ qo,
    short* __restrict__ ko, short* __restrict__ vo) {
  const float* src = blockIdx.z == 0 ? q : blockIdx.z == 1 ? k : v;
  short* dst       = blockIdx.z == 0 ? qo : blockIdx.z == 1 ? ko : vo;
  size_t i = ((size_t)blockIdx.x * 256 + threadIdx.x) * 4;
  float4 f = *(const float4*)(src + i);
  short4 s;
  s.x = f2bf(f.x); s.y = f2bf(f.y); s.z = f2bf(f.z); s.w = f2bf(f.w);
  *(short4*)(dst + i) = s;
}

// ---------------------------------------------------------------------------
// Wq/Wk/Wv [16][1024][64] fp32 -> WT [n=h*64+e][k=d] bf16 (transposed).
// grid (16 dtiles, 16 heads, 3), block 256, tile 64x64.
// ---------------------------------------------------------------------------
__global__ __launch_bounds__(256) void conv_w(
    const float* __restrict__ Wq, const float* __restrict__ Wk,
    const float* __restrict__ Wv, short* __restrict__ qT,
    short* __restrict__ kT, short* __restrict__ vT) {
  __shared__ short sT[64 * 72];
  const float* W = blockIdx.z == 0 ? Wq : blockIdx.z == 1 ? Wk : Wv;
  short* WT      = blockIdx.z == 0 ? qT : blockIdx.z == 1 ? kT : vT;
  const int h = blockIdx.y, d0 = blockIdx.x * 64;
  const int t = threadIdx.x, r = t >> 2, c0 = (t & 3) * 16;
  const float4* src = (const float4*)(W + ((size_t)h * DD + d0 + r) * HD + c0);
  float4 f0 = src[0], f1 = src[1], f2 = src[2], f3 = src[3];
  const float ff[16] = {f0.x, f0.y, f0.z, f0.w, f1.x, f1.y, f1.z, f1.w,
                        f2.x, f2.y, f2.z, f2.w, f3.x, f3.y, f3.z, f3.w};
#pragma unroll
  for (int j = 0; j < 16; ++j) sT[r * 72 + c0 + j] = f2bf(ff[j]);
  __syncthreads();
  alignas(16) short tmp[16];
#pragma unroll
  for (int j = 0; j < 16; ++j) tmp[j] = sT[(c0 + j) * 72 + r];
  short* dst = WT + ((size_t)h * HD + r) * DD + d0 + c0;
  *(int4*)(dst) = *(const int4*)(tmp);
  *(int4*)(dst + 8) = *(const int4*)(tmp + 8);
}

// ---------------------------------------------------------------------------
// Wo [1024][1024] fp32 -> WoT [n][k] bf16 transposed. grid (16,16), tile 64x64
// ---------------------------------------------------------------------------
__global__ __launch_bounds__(256) void conv_wo(const float* __restrict__ Wo,
                                               short* __restrict__ WoT) {
  __shared__ short sT[64 * 72];
  const int k0 = blockIdx.x * 64, n0 = blockIdx.y * 64;
  const int t = threadIdx.x, r = t >> 2, c0 = (t & 3) * 16;
  const float4* src = (const float4*)(Wo + (size_t)(k0 + r) * DD + n0 + c0);
  float4 f0 = src[0], f1 = src[1], f2 = src[2], f3 = src[3];
  const float ff[16] = {f0.x, f0.y, f0.z, f0.w, f1.x, f1.y, f1.z, f1.w,
                        f2.x, f2.y, f2.z, f2.w, f3.x, f3.y, f3.z, f3.w};
#pragma unroll
  for (int j = 0; j < 16; ++j) sT[r * 72 + c0 + j] = f2bf(ff[j]);
  __syncthreads();
  alignas(16) short tmp[16];
#pragma unroll
  for (int j = 0; j < 16; ++j) tmp[j] = sT[(c0 + j) * 72 + r];
  short* dst = WoT + (size_t)(n0 + r) * DD + k0 + c0;
  *(int4*)(dst) = *(const int4*)(tmp);
  *(int4*)(dst + 8) = *(const int4*)(tmp + 8);
}

// ---------------------------------------------------------------------------
// Projection GEMM: ph = x @ W, M=4096, N=1024, K=1024. Output PLAIN [m][n]
// (head h occupies cols h*64..h*64+63). BM=BN=128 BK=32. grid (32, 8, 3).
// ---------------------------------------------------------------------------
__global__ __launch_bounds__(256) void proj(
    const short* __restrict__ xq, const short* __restrict__ xk,
    const short* __restrict__ xv, const short* __restrict__ WqT,
    const short* __restrict__ WkT, const short* __restrict__ WvT,
    short* __restrict__ qh, short* __restrict__ kh, short* __restrict__ vh) {
  __shared__ short sA[128 * 32];
  __shared__ short sB[128 * 32];
  const int which = blockIdx.z;
  const short* X  = which == 0 ? xq : which == 1 ? xk : xv;
  const short* WT = which == 0 ? WqT : which == 1 ? WkT : WvT;
  short* dst      = which == 0 ? qh : which == 1 ? kh : vh;
  const int m0 = blockIdx.x * 128, n0 = blockIdx.y * 128;
  const int tid = threadIdx.x, wid = tid >> 6, lane = tid & 63;
  const int quad = lane >> 4, l16 = lane & 15;
  const int wr = wid >> 1, wc = wid & 1;

  floatx4 acc[4][4] = {};
  for (int k0 = 0; k0 < DD; k0 += 32) {
    __syncthreads();
#pragma unroll
    for (int i = 0; i < 2; ++i) {
      const int c = wid * 2 + i;
      const int ci = c * 64 + lane;
      load_lds16(X + (size_t)(m0 + (ci >> 2)) * DD + k0 + (ci & 3) * 8,
                 &sA[c * 512]);
      load_lds16(WT + (size_t)(n0 + (ci >> 2)) * DD + k0 + (ci & 3) * 8,
                 &sB[c * 512]);
    }
    __syncthreads();
    bf16x8 af[4], bfr[4];
#pragma unroll
    for (int mi = 0; mi < 4; ++mi)
      af[mi] = *(const bf16x8*)&sA[(wr * 64 + mi * 16 + l16) * 32 + quad * 8];
#pragma unroll
    for (int ni = 0; ni < 4; ++ni)
      bfr[ni] = *(const bf16x8*)&sB[(wc * 64 + ni * 16 + l16) * 32 + quad * 8];
#pragma unroll
    for (int mi = 0; mi < 4; ++mi)
#pragma unroll
      for (int ni = 0; ni < 4; ++ni)
        acc[mi][ni] = __builtin_amdgcn_mfma_f32_16x16x32_bf16(
            af[mi], bfr[ni], acc[mi][ni], 0, 0, 0);
  }
  const float scale = (which == 0) ? 0.125f : 1.0f;  // fold 1/sqrt(64) into Q
#pragma unroll
  for (int mi = 0; mi < 4; ++mi)
#pragma unroll
    for (int ni = 0; ni < 4; ++ni)
#pragma unroll
      for (int r2 = 0; r2 < 4; ++r2) {
        const int m = m0 + wr * 64 + mi * 16 + quad * 4 + r2;
        const int n = n0 + wc * 64 + ni * 16 + l16;
        dst[(size_t)m * DD + n] = f2bf(acc[mi][ni][r2] * scale);
      }
}

// ---------------------------------------------------------------------------
// vh [m=b*2048+s][1024] bf16 -> vhT [bh][e][2048] bf16. grid (32 stiles, 32 bh)
// ---------------------------------------------------------------------------
__global__ __launch_bounds__(256) void vtrans(const short* __restrict__ vh,
                                              short* __restrict__ vhT) {
  __shared__ short sT[64 * 72];
  const int bh = blockIdx.y, b = bh >> 4, h = bh & 15, s0 = blockIdx.x * 64;
  const int t = threadIdx.x, r = t >> 2, c0 = (t & 3) * 16;
  const short* src = vh + (size_t)(b * SS + s0 + r) * DD + h * HD + c0;
  *(int4*)&sT[r * 72 + c0] = *(const int4*)src;
  *(int4*)&sT[r * 72 + c0 + 8] = *(const int4*)(src + 8);
  __syncthreads();
  alignas(16) short tmp[16];
#pragma unroll
  for (int j = 0; j < 16; ++j) tmp[j] = sT[(c0 + j) * 72 + r];
  short* dst = vhT + ((size_t)bh * HD + r) * SS + s0 + c0;
  *(int4*)(dst) = *(const int4*)(tmp);
  *(int4*)(dst + 8) = *(const int4*)(tmp + 8);
}

// ---------------------------------------------------------------------------
// Flash attention, bf16 MFMA, deferred softmax (no max-tracking -> t-additive
// partials). Block = 256 (4 waves) ALL on the same 32-row q-strip; wave w
// computes tiles w, w+4, w+8... and partial (O_w, l_w); cross-wave combine is
// an element-wise add through LDS (3 barriers). grid (64 strips, 32 bh).
// Causal cndmask only on the (wave-uniform) diagonal tile.
// X output flat [b][h][s][e] — the reference's RAW VIEW (no head transpose).
// ---------------------------------------------------------------------------
__global__ __launch_bounds__(256) void attn(
    const short* __restrict__ qh, const short* __restrict__ kh,
    const short* __restrict__ vhT, const int* __restrict__ mask,
    short* __restrict__ X) {
  __shared__ union {
    short sP[4][32 * 72];   // per-wave P tile (main loop), padded stride 72
    float red[2][40 * 64];  // cross-wave reduction slots (after barrier)
  } u;
  const int tid = threadIdx.x, wid = tid >> 6, lane = tid & 63;
  const int quad = lane >> 4, l16 = lane & 15;
  const int strip = (int)gridDim.x - 1 - blockIdx.x;  // heavy strips first
  const int bh = blockIdx.y, b = bh >> 4, h = bh & 15;
  const int row0 = strip * 32;

  const short* Q  = qh + (size_t)b * SS * DD + h * HD;
  const short* K  = kh + (size_t)b * SS * DD + h * HD;
  const short* Vt = vhT + (size_t)bh * HD * SS;
  const int* mk = mask + b * SS;

  // Q fragments: A-layout, m = l16 (row row0+mi*16+l16), k = ks*32+quad*8
  bf16x8 aq[2][2];
#pragma unroll
  for (int mi = 0; mi < 2; ++mi)
#pragma unroll
    for (int ks = 0; ks < 2; ++ks)
      aq[mi][ks] = *(const bf16x8*)(Q + (size_t)(row0 + mi * 16 + l16) * DD +
                                    ks * 32 + quad * 8);
  int mrow[2][4];
#pragma unroll
  for (int mi = 0; mi < 2; ++mi)
#pragma unroll
    for (int r2 = 0; r2 < 4; ++r2)
      mrow[mi][r2] = mk[row0 + mi * 16 + quad * 4 + r2];

  floatx4 o[2][4] = {};
  float lacc[2][4];
#pragma unroll
  for (int mi = 0; mi < 2; ++mi)
#pragma unroll
    for (int r2 = 0; r2 < 4; ++r2) lacc[mi][r2] = 0.f;

  const int ntiles = (row0 >> 6) + 1;  // causal extent in 64-col tiles
  for (int tb = wid; tb < ntiles; tb += 4) {
    const int t0 = tb * 64;
    // K fragments from global (L2-resident): B-layout n = t-row, k contiguous
    bf16x8 bk[4][2];
#pragma unroll
    for (int ni = 0; ni < 4; ++ni)
#pragma unroll
      for (int ks = 0; ks < 2; ++ks)
        bk[ni][ks] = *(const bf16x8*)(K + (size_t)(t0 + ni * 16 + l16) * DD +
                                      ks * 32 + quad * 8);
    int mt[4];
#pragma unroll
    for (int ni = 0; ni < 4; ++ni) mt[ni] = mk[t0 + ni * 16 + l16];
    const bool diag = (tb == ntiles - 1);  // wave-uniform

#pragma unroll
    for (int mi = 0; mi < 2; ++mi) {
      floatx4 s[4] = {};
#pragma unroll
      for (int ks = 0; ks < 2; ++ks)
#pragma unroll
        for (int ni = 0; ni < 4; ++ni)
          s[ni] = __builtin_amdgcn_mfma_f32_16x16x32_bf16(
              aq[mi][ks], bk[ni][ks], s[ni], 0, 0, 0);
#pragma unroll
      for (int ni = 0; ni < 4; ++ni)
#pragma unroll
        for (int r2 = 0; r2 < 4; ++r2) {
          float x = s[ni][r2];
          if (mrow[mi][r2] | mt[ni]) x = 0.f;  // reference: pad -> 0.0 first
          float p = __expf(x);
          if (diag) {  // causal (wins over pad) — diagonal tile only
            const int row = row0 + mi * 16 + quad * 4 + r2;
            const int col = t0 + ni * 16 + l16;
            if (col > row) p = 0.f;
          }
          lacc[mi][r2] += p;
          u.sP[wid][(mi * 16 + quad * 4 + r2) * 72 + ni * 16 + l16] = f2bf(p);
        }
    }
    // O += P V : P via per-wave LDS round-trip (A-layout); Vt B-frags global
#pragma unroll
    for (int ks = 0; ks < 2; ++ks) {
      bf16x8 ap[2], bv[4];
#pragma unroll
      for (int mi = 0; mi < 2; ++mi)
        ap[mi] = *(const bf16x8*)&u.sP[wid][(mi * 16 + l16) * 72 + ks * 32 +
                                            quad * 8];
#pragma unroll
      for (int ei = 0; ei < 4; ++ei)
        bv[ei] = *(const bf16x8*)(Vt + (size_t)(ei * 16 + l16) * SS + t0 +
                                  ks * 32 + quad * 8);
#pragma unroll
      for (int mi = 0; mi < 2; ++mi)
#pragma unroll
        for (int ei = 0; ei < 4; ++ei)
          o[mi][ei] = __builtin_amdgcn_mfma_f32_16x16x32_bf16(
              ap[mi], bv[ei], o[mi][ei], 0, 0, 0);
    }
  }

  // ---- cross-wave combine: element-major [j][64] slots, pure adds ----
  __syncthreads();  // sP dead from here; red aliases it
  auto dump = [&](float* dst) {
    int j = 0;
#pragma unroll
    for (int mi = 0; mi < 2; ++mi)
#pragma unroll
      for (int ei = 0; ei < 4; ++ei)
#pragma unroll
        for (int r2 = 0; r2 < 4; ++r2) dst[(j++) * 64 + lane] = o[mi][ei][r2];
#pragma unroll
    for (int mi = 0; mi < 2; ++mi)
#pragma unroll
      for (int r2 = 0; r2 < 4; ++r2) dst[(j++) * 64 + lane] = lacc[mi][r2];
  };
  auto accum = [&](const float* srcp) {
    int j = 0;
#pragma unroll
    for (int mi = 0; mi < 2; ++mi)
#pragma unroll
      for (int ei = 0; ei < 4; ++ei)
#pragma unroll
        for (int r2 = 0; r2 < 4; ++r2) o[mi][ei][r2] += srcp[(j++) * 64 + lane];
#pragma unroll
    for (int mi = 0; mi < 2; ++mi)
#pragma unroll
      for (int r2 = 0; r2 < 4; ++r2) lacc[mi][r2] += srcp[(j++) * 64 + lane];
  };
  if (wid == 1) dump(u.red[0]);
  if (wid == 3) dump(u.red[1]);
  __syncthreads();
  if (wid == 0) accum(u.red[0]);
  if (wid == 2) accum(u.red[1]);
  __syncthreads();
  if (wid == 2) dump(u.red[0]);
  __syncthreads();
  if (wid == 0) {
    accum(u.red[0]);
#pragma unroll
    for (int mi = 0; mi < 2; ++mi)
#pragma unroll
      for (int r2 = 0; r2 < 4; ++r2) {
        const float inv = 1.0f / redsum16(lacc[mi][r2]);
        const int srow = row0 + mi * 16 + quad * 4 + r2;
#pragma unroll
        for (int ei = 0; ei < 4; ++ei)
          X[((size_t)bh * SS + srow) * HD + ei * 16 + l16] =
              f2bf(o[mi][ei][r2] * inv);
      }
  }
}

// ---------------------------------------------------------------------------
// out = X[4096,1024] @ Wo, via WoT[n][k]. BM=128 BN=64 BK=32, 256 threads.
// grid (32, 16) = 512 blocks (2/CU). fp32 output.
// ---------------------------------------------------------------------------
__global__ __launch_bounds__(256) void oproj(const short* __restrict__ X,
                                             const short* __restrict__ WoT,
                                             float* __restrict__ out) {
  __shared__ short sA[128 * 32];
  __shared__ short sB[64 * 32];
  const int m0 = blockIdx.x * 128, n0 = blockIdx.y * 64;
  const int tid = threadIdx.x, wid = tid >> 6, lane = tid & 63;
  const int quad = lane >> 4, l16 = lane & 15;
  const int wr = wid >> 1, wc = wid & 1;  // 2 row-groups x 2 col-groups

  floatx4 acc[4][2] = {};
  for (int k0 = 0; k0 < DD; k0 += 32) {
    __syncthreads();
#pragma unroll
    for (int i = 0; i < 2; ++i) {
      const int c = wid * 2 + i;
      const int ci = c * 64 + lane;
      load_lds16(X + (size_t)(m0 + (ci >> 2)) * DD + k0 + (ci & 3) * 8,
                 &sA[c * 512]);
    }
    {
      const int ci = wid * 64 + lane;
      load_lds16(WoT + (size_t)(n0 + (ci >> 2)) * DD + k0 + (ci & 3) * 8,
                 &sB[wid * 512]);
    }
    __syncthreads();
    bf16x8 af[4], bfr[2];
#pragma unroll
    for (int mi = 0; mi < 4; ++mi)
      af[mi] = *(const bf16x8*)&sA[(wr * 64 + mi * 16 + l16) * 32 + quad * 8];
#pragma unroll
    for (int ni = 0; ni < 2; ++ni)
      bfr[ni] = *(const bf16x8*)&sB[(wc * 32 + ni * 16 + l16) * 32 + quad * 8];
#pragma unroll
    for (int mi = 0; mi < 4; ++mi)
#pragma unroll
      for (int ni = 0; ni < 2; ++ni)
        acc[mi][ni] = __builtin_amdgcn_mfma_f32_16x16x32_bf16(
            af[mi], bfr[ni], acc[mi][ni], 0, 0, 0);
  }
#pragma unroll
  for (int mi = 0; mi < 4; ++mi)
#pragma unroll
    for (int ni = 0; ni < 2; ++ni)
#pragma unroll
      for (int r2 = 0; r2 < 4; ++r2)
        out[(size_t)(m0 + wr * 64 + mi * 16 + quad * 4 + r2) * DD + n0 +
            wc * 32 + ni * 16 + l16] = acc[mi][ni][r2];
}

// ---------------------------------------------------------------------------
extern "C" void kernel_launch(void* const* d_in, const int* in_sizes, int n_in,
                              void* d_out, int out_size, void* d_ws,
                              size_t ws_size, hipStream_t stream) {
  const float* q  = (const float*)d_in[0];
  const float* k  = (const float*)d_in[1];
  const float* v  = (const float*)d_in[2];
  const float* Wq = (const float*)d_in[3];
  const float* Wk = (const float*)d_in[4];
  const float* Wv = (const float*)d_in[5];
  const float* Wo = (const float*)d_in[6];
  const int* mask = (const int*)d_in[7];
  float* out = (float*)d_out;

  // workspace layout (shorts); X aliases qb, vhT aliases kb (dead by then)
  short* ws = (short*)d_ws;
  const size_t NIN = (size_t)BB * SS * DD;  // 4,194,304
  const size_t NWH = (size_t)HH * HD * DD;  // 1,048,576
  short* qb  = ws;        // also X
  short* kb  = ws + NIN;  // also vhT
  short* vb  = ws + 2 * NIN;
  short* WqT = ws + 3 * NIN;
  short* WkT = WqT + NWH;
  short* WvT = WkT + NWH;
  short* WoT = WvT + NWH;
  short* qhp = WoT + (size_t)DD * DD;
  short* khp = qhp + NIN;
  short* vhp = khp + NIN;
  short* Xp  = qb;
  short* vhT = kb;

  conv_in<<<dim3(4096, 1, 3), 256, 0, stream>>>(q, k, v, qb, kb, vb);
  conv_w<<<dim3(16, 16, 3), 256, 0, stream>>>(Wq, Wk, Wv, WqT, WkT, WvT);
  conv_wo<<<dim3(16, 16), 256, 0, stream>>>(Wo, WoT);
  proj<<<dim3(32, 8, 3), 256, 0, stream>>>(qb, kb, vb, WqT, WkT, WvT, qhp,
                                           khp, vhp);
  vtrans<<<dim3(32, 32), 256, 0, stream>>>(vhp, vhT);
  attn<<<dim3(64, 32), 256, 0, stream>>>(qhp, khp, vhT, mask, Xp);
  oproj<<<dim3(32, 16), 256, 0, stream>>>(Xp, WoT, out);
}

// Round 7
// 243.436 us; speedup vs baseline: 1.1840x; 1.1840x over previous
//
#include <hip/hip_runtime.h>
#include <hip/hip_bf16.h>

#define BB 2
#define SS 2048
#define DD 1024
#define HH 16
#define HD 64

typedef __attribute__((ext_vector_type(8))) short bf16x8;
typedef __attribute__((ext_vector_type(4))) float floatx4;

__device__ __forceinline__ short f2bf(float x) {
  __hip_bfloat16 h = __float2bfloat16(x);
  return __builtin_bit_cast(short, h);
}

// async global->LDS, 16B per lane; LDS dest is wave-uniform base + lane*16
__device__ __forceinline__ void load_lds16(const void* g, void* l) {
  __builtin_amdgcn_global_load_lds(
      (const __attribute__((address_space(1))) unsigned int*)g,
      (__attribute__((address_space(3))) unsigned int*)l, 16, 0, 0);
}

__device__ __forceinline__ float redsum16(float v) {
  v += __shfl_xor(v, 1, 64);
  v += __shfl_xor(v, 2, 64);
  v += __shfl_xor(v, 4, 64);
  v += __shfl_xor(v, 8, 64);
  return v;
}

// ---------------------------------------------------------------------------
// prep: fused conv_in (q,k,v fp32->bf16) + conv_w (Wq/Wk/Wv transpose) +
// conv_wo (Wo transpose). 1D grid 13312, block 256.
//   blk <  12288 : conv_in   (which = blk>>12, x = blk&4095)
//   blk <  13056 : conv_w    (which, dtile, h)
//   else         : conv_wo   (ktile, ntile)
// ---------------------------------------------------------------------------
__global__ __launch_bounds__(256) void prep(
    const float* __restrict__ q, const float* __restrict__ k,
    const float* __restrict__ v, const float* __restrict__ Wq,
    const float* __restrict__ Wk, const float* __restrict__ Wv,
    const float* __restrict__ Wo, short* __restrict__ qo,
    short* __restrict__ ko, short* __restrict__ vo, short* __restrict__ qT,
    short* __restrict__ kT, short* __restrict__ vT, short* __restrict__ WoT) {
  __shared__ short sT[64 * 72];
  const int blk = blockIdx.x;
  if (blk < 12288) {
    const int which = blk >> 12, x = blk & 4095;
    const float* src = which == 0 ? q : which == 1 ? k : v;
    short* dst       = which == 0 ? qo : which == 1 ? ko : vo;
    size_t i = ((size_t)x * 256 + threadIdx.x) * 4;
    float4 f = *(const float4*)(src + i);
    short4 s;
    s.x = f2bf(f.x); s.y = f2bf(f.y); s.z = f2bf(f.z); s.w = f2bf(f.w);
    *(short4*)(dst + i) = s;
    return;
  }
  const int t = threadIdx.x, r = t >> 2, c0 = (t & 3) * 16;
  const float* src;
  short* dst;
  if (blk < 13056) {  // conv_w: W[h][1024][64] -> WT[h*64+e][1024]
    const int b2 = blk - 12288, which = b2 >> 8, rr = b2 & 255;
    const int dtile = rr & 15, h = rr >> 4, d0 = dtile * 64;
    const float* W = which == 0 ? Wq : which == 1 ? Wk : Wv;
    short* WT      = which == 0 ? qT : which == 1 ? kT : vT;
    src = W + ((size_t)h * DD + d0 + r) * HD + c0;
    dst = WT + ((size_t)h * HD + r) * DD + d0 + c0;
  } else {  // conv_wo: Wo[1024][1024] -> WoT[n][k]
    const int b3 = blk - 13056;
    const int k0 = (b3 & 15) * 64, n0 = (b3 >> 4) * 64;
    src = Wo + (size_t)(k0 + r) * DD + n0 + c0;
    dst = WoT + (size_t)(n0 + r) * DD + k0 + c0;
  }
  const float4* s4 = (const float4*)src;
  float4 f0 = s4[0], f1 = s4[1], f2 = s4[2], f3 = s4[3];
  const float ff[16] = {f0.x, f0.y, f0.z, f0.w, f1.x, f1.y, f1.z, f1.w,
                        f2.x, f2.y, f2.z, f2.w, f3.x, f3.y, f3.z, f3.w};
#pragma unroll
  for (int j = 0; j < 16; ++j) sT[r * 72 + c0 + j] = f2bf(ff[j]);
  __syncthreads();
  alignas(16) short tmp[16];
#pragma unroll
  for (int j = 0; j < 16; ++j) tmp[j] = sT[(c0 + j) * 72 + r];
  *(int4*)(dst) = *(const int4*)(tmp);
  *(int4*)(dst + 8) = *(const int4*)(tmp + 8);
}

// ---------------------------------------------------------------------------
// Projection GEMM: ph = x @ W, M=4096, N=1024, K=1024. Output PLAIN [m][n].
// 1D grid 768, XCD-decoded so the n-block (head pair) lands on the XCD that
// attn will use for those heads: xcd = 4*(m>=2048) + (head_pair>>1).
// ---------------------------------------------------------------------------
__global__ __launch_bounds__(256) void proj(
    const short* __restrict__ xq, const short* __restrict__ xk,
    const short* __restrict__ xv, const short* __restrict__ WqT,
    const short* __restrict__ WkT, const short* __restrict__ WvT,
    short* __restrict__ qh, short* __restrict__ kh, short* __restrict__ vh) {
  __shared__ short sA[128 * 32];
  __shared__ short sB[128 * 32];
  const int xcd = blockIdx.x & 7, tt = blockIdx.x >> 3;
  const int which = tt >> 5;              // 0..2
  const int rest = tt & 31;
  const int j = ((xcd & 3) << 1) | (rest >> 4);   // n-block 0..7
  const int i = ((xcd >> 2) << 4) | (rest & 15);  // m-block 0..31
  const short* X  = which == 0 ? xq : which == 1 ? xk : xv;
  const short* WT = which == 0 ? WqT : which == 1 ? WkT : WvT;
  short* dst      = which == 0 ? qh : which == 1 ? kh : vh;
  const int m0 = i * 128, n0 = j * 128;
  const int tid = threadIdx.x, wid = tid >> 6, lane = tid & 63;
  const int quad = lane >> 4, l16 = lane & 15;
  const int wr = wid >> 1, wc = wid & 1;

  floatx4 acc[4][4] = {};
  for (int k0 = 0; k0 < DD; k0 += 32) {
    __syncthreads();
#pragma unroll
    for (int ii = 0; ii < 2; ++ii) {
      const int c = wid * 2 + ii;
      const int ci = c * 64 + lane;
      load_lds16(X + (size_t)(m0 + (ci >> 2)) * DD + k0 + (ci & 3) * 8,
                 &sA[c * 512]);
      load_lds16(WT + (size_t)(n0 + (ci >> 2)) * DD + k0 + (ci & 3) * 8,
                 &sB[c * 512]);
    }
    __syncthreads();
    bf16x8 af[4], bfr[4];
#pragma unroll
    for (int mi = 0; mi < 4; ++mi)
      af[mi] = *(const bf16x8*)&sA[(wr * 64 + mi * 16 + l16) * 32 + quad * 8];
#pragma unroll
    for (int ni = 0; ni < 4; ++ni)
      bfr[ni] = *(const bf16x8*)&sB[(wc * 64 + ni * 16 + l16) * 32 + quad * 8];
#pragma unroll
    for (int mi = 0; mi < 4; ++mi)
#pragma unroll
      for (int ni = 0; ni < 4; ++ni)
        acc[mi][ni] = __builtin_amdgcn_mfma_f32_16x16x32_bf16(
            af[mi], bfr[ni], acc[mi][ni], 0, 0, 0);
  }
  const float scale = (which == 0) ? 0.125f : 1.0f;  // fold 1/sqrt(64) into Q
#pragma unroll
  for (int mi = 0; mi < 4; ++mi)
#pragma unroll
    for (int ni = 0; ni < 4; ++ni)
#pragma unroll
      for (int r2 = 0; r2 < 4; ++r2) {
        const int m = m0 + wr * 64 + mi * 16 + quad * 4 + r2;
        const int n = n0 + wc * 64 + ni * 16 + l16;
        dst[(size_t)m * DD + n] = f2bf(acc[mi][ni][r2] * scale);
      }
}

// ---------------------------------------------------------------------------
// vh [m][1024] -> vhT [bh][e][2048]. 1D grid 1024, XCD-decoded to match attn:
// bh group {4x..4x+3} on XCD x.
// ---------------------------------------------------------------------------
__global__ __launch_bounds__(256) void vtrans(const short* __restrict__ vh,
                                              short* __restrict__ vhT) {
  __shared__ short sT[64 * 72];
  const int xcd = blockIdx.x & 7, slot = blockIdx.x >> 3;  // 0..127
  const int bh = (xcd << 2) | (slot & 3), stile = slot >> 2;
  const int b = bh >> 4, h = bh & 15, s0 = stile * 64;
  const int t = threadIdx.x, r = t >> 2, c0 = (t & 3) * 16;
  const short* src = vh + (size_t)(b * SS + s0 + r) * DD + h * HD + c0;
  *(int4*)&sT[r * 72 + c0] = *(const int4*)src;
  *(int4*)&sT[r * 72 + c0 + 8] = *(const int4*)(src + 8);
  __syncthreads();
  alignas(16) short tmp[16];
#pragma unroll
  for (int j = 0; j < 16; ++j) tmp[j] = sT[(c0 + j) * 72 + r];
  short* dst = vhT + ((size_t)bh * HD + r) * SS + s0 + c0;
  *(int4*)(dst) = *(const int4*)(tmp);
  *(int4*)(dst + 8) = *(const int4*)(tmp + 8);
}

// ---------------------------------------------------------------------------
// Flash attention, bf16 MFMA, deferred softmax (t-additive partials), t-split
// across the block's 4 waves (combine = LDS adds). 1D grid 2048, XCD-decoded:
// all blocks for bh-group {4x..4x+3} land on XCD x (blockIdx%8 heuristic), so
// each head's Q/K/Vt slices stay resident in that XCD's 4MB L2. Heavy strips
// dispatched first within each XCD. V-fragment loads hoisted to the loop top
// so they overlap QK+softmax. X out = flat [b][h][s][e] (reference raw view).
// ---------------------------------------------------------------------------
__global__ __launch_bounds__(256) void attn(
    const short* __restrict__ qh, const short* __restrict__ kh,
    const short* __restrict__ vhT, const int* __restrict__ mask,
    short* __restrict__ X) {
  __shared__ union {
    short sP[4][32 * 72];   // per-wave P tile (main loop), padded stride 72
    float red[2][40 * 64];  // cross-wave reduction slots (after barrier)
  } u;
  const int tid = threadIdx.x, wid = tid >> 6, lane = tid & 63;
  const int quad = lane >> 4, l16 = lane & 15;
  const int xcd = blockIdx.x & 7, slot = blockIdx.x >> 3;  // 0..255
  const int bh = (xcd << 2) | (slot & 3);
  const int strip = 63 - (slot >> 2);  // heavy strips first per XCD
  const int b = bh >> 4, h = bh & 15;
  const int row0 = strip * 32;

  const short* Q  = qh + (size_t)b * SS * DD + h * HD;
  const short* K  = kh + (size_t)b * SS * DD + h * HD;
  const short* Vt = vhT + (size_t)bh * HD * SS;
  const int* mk = mask + b * SS;

  // Q fragments: A-layout, m = l16 (row row0+mi*16+l16), k = ks*32+quad*8
  bf16x8 aq[2][2];
#pragma unroll
  for (int mi = 0; mi < 2; ++mi)
#pragma unroll
    for (int ks = 0; ks < 2; ++ks)
      aq[mi][ks] = *(const bf16x8*)(Q + (size_t)(row0 + mi * 16 + l16) * DD +
                                    ks * 32 + quad * 8);
  int mrow[2][4];
#pragma unroll
  for (int mi = 0; mi < 2; ++mi)
#pragma unroll
    for (int r2 = 0; r2 < 4; ++r2)
      mrow[mi][r2] = mk[row0 + mi * 16 + quad * 4 + r2];

  floatx4 o[2][4] = {};
  float lacc[2][4];
#pragma unroll
  for (int mi = 0; mi < 2; ++mi)
#pragma unroll
    for (int r2 = 0; r2 < 4; ++r2) lacc[mi][r2] = 0.f;

  const int ntiles = (row0 >> 6) + 1;  // causal extent in 64-col tiles
  for (int tb = wid; tb < ntiles; tb += 4) {
    const int t0 = tb * 64;
    // Issue ALL of this tile's global loads up front (K then V): V-latency
    // overlaps QK + softmax; compiler waits per first use.
    bf16x8 bk[4][2], bv[4][2];
#pragma unroll
    for (int ni = 0; ni < 4; ++ni)
#pragma unroll
      for (int ks = 0; ks < 2; ++ks)
        bk[ni][ks] = *(const bf16x8*)(K + (size_t)(t0 + ni * 16 + l16) * DD +
                                      ks * 32 + quad * 8);
#pragma unroll
    for (int ei = 0; ei < 4; ++ei)
#pragma unroll
      for (int ks = 0; ks < 2; ++ks)
        bv[ei][ks] = *(const bf16x8*)(Vt + (size_t)(ei * 16 + l16) * SS + t0 +
                                      ks * 32 + quad * 8);
    int mt[4];
#pragma unroll
    for (int ni = 0; ni < 4; ++ni) mt[ni] = mk[t0 + ni * 16 + l16];
    const bool diag = (tb == ntiles - 1);  // wave-uniform

#pragma unroll
    for (int mi = 0; mi < 2; ++mi) {
      floatx4 s[4] = {};
#pragma unroll
      for (int ks = 0; ks < 2; ++ks)
#pragma unroll
        for (int ni = 0; ni < 4; ++ni)
          s[ni] = __builtin_amdgcn_mfma_f32_16x16x32_bf16(
              aq[mi][ks], bk[ni][ks], s[ni], 0, 0, 0);
#pragma unroll
      for (int ni = 0; ni < 4; ++ni)
#pragma unroll
        for (int r2 = 0; r2 < 4; ++r2) {
          float x = s[ni][r2];
          if (mrow[mi][r2] | mt[ni]) x = 0.f;  // reference: pad -> 0.0 first
          float p = __expf(x);
          if (diag) {  // causal (wins over pad) — diagonal tile only
            const int row = row0 + mi * 16 + quad * 4 + r2;
            const int col = t0 + ni * 16 + l16;
            if (col > row) p = 0.f;
          }
          lacc[mi][r2] += p;
          u.sP[wid][(mi * 16 + quad * 4 + r2) * 72 + ni * 16 + l16] = f2bf(p);
        }
    }
    // O += P V : P via per-wave LDS round-trip (A-layout); bv already loaded
#pragma unroll
    for (int ks = 0; ks < 2; ++ks) {
      bf16x8 ap[2];
#pragma unroll
      for (int mi = 0; mi < 2; ++mi)
        ap[mi] = *(const bf16x8*)&u.sP[wid][(mi * 16 + l16) * 72 + ks * 32 +
                                            quad * 8];
#pragma unroll
      for (int mi = 0; mi < 2; ++mi)
#pragma unroll
        for (int ei = 0; ei < 4; ++ei)
          o[mi][ei] = __builtin_amdgcn_mfma_f32_16x16x32_bf16(
              ap[mi], bv[ei][ks], o[mi][ei], 0, 0, 0);
    }
  }

  // ---- cross-wave combine: element-major [j][64] slots, pure adds ----
  __syncthreads();  // sP dead from here; red aliases it
  auto dump = [&](float* dst) {
    int j = 0;
#pragma unroll
    for (int mi = 0; mi < 2; ++mi)
#pragma unroll
      for (int ei = 0; ei < 4; ++ei)
#pragma unroll
        for (int r2 = 0; r2 < 4; ++r2) dst[(j++) * 64 + lane] = o[mi][ei][r2];
#pragma unroll
    for (int mi = 0; mi < 2; ++mi)
#pragma unroll
      for (int r2 = 0; r2 < 4; ++r2) dst[(j++) * 64 + lane] = lacc[mi][r2];
  };
  auto accum = [&](const float* srcp) {
    int j = 0;
#pragma unroll
    for (int mi = 0; mi < 2; ++mi)
#pragma unroll
      for (int ei = 0; ei < 4; ++ei)
#pragma unroll
        for (int r2 = 0; r2 < 4; ++r2) o[mi][ei][r2] += srcp[(j++) * 64 + lane];
#pragma unroll
    for (int mi = 0; mi < 2; ++mi)
#pragma unroll
      for (int r2 = 0; r2 < 4; ++r2) lacc[mi][r2] += srcp[(j++) * 64 + lane];
  };
  if (wid == 1) dump(u.red[0]);
  if (wid == 3) dump(u.red[1]);
  __syncthreads();
  if (wid == 0) accum(u.red[0]);
  if (wid == 2) accum(u.red[1]);
  __syncthreads();
  if (wid == 2) dump(u.red[0]);
  __syncthreads();
  if (wid == 0) {
    accum(u.red[0]);
#pragma unroll
    for (int mi = 0; mi < 2; ++mi)
#pragma unroll
      for (int r2 = 0; r2 < 4; ++r2) {
        const float inv = 1.0f / redsum16(lacc[mi][r2]);
        const int srow = row0 + mi * 16 + quad * 4 + r2;
#pragma unroll
        for (int ei = 0; ei < 4; ++ei)
          X[((size_t)bh * SS + srow) * HD + ei * 16 + l16] =
              f2bf(o[mi][ei][r2] * inv);
      }
  }
}

// ---------------------------------------------------------------------------
// out = X[4096,1024] @ Wo, via WoT[n][k]. BM=128 BN=64 BK=32, 256 threads.
// grid (32, 16) = 512 blocks (2/CU). fp32 output.
// ---------------------------------------------------------------------------
__global__ __launch_bounds__(256) void oproj(const short* __restrict__ X,
                                             const short* __restrict__ WoT,
                                             float* __restrict__ out) {
  __shared__ short sA[128 * 32];
  __shared__ short sB[64 * 32];
  const int m0 = blockIdx.x * 128, n0 = blockIdx.y * 64;
  const int tid = threadIdx.x, wid = tid >> 6, lane = tid & 63;
  const int quad = lane >> 4, l16 = lane & 15;
  const int wr = wid >> 1, wc = wid & 1;

  floatx4 acc[4][2] = {};
  for (int k0 = 0; k0 < DD; k0 += 32) {
    __syncthreads();
#pragma unroll
    for (int i = 0; i < 2; ++i) {
      const int c = wid * 2 + i;
      const int ci = c * 64 + lane;
      load_lds16(X + (size_t)(m0 + (ci >> 2)) * DD + k0 + (ci & 3) * 8,
                 &sA[c * 512]);
    }
    {
      const int ci = wid * 64 + lane;
      load_lds16(WoT + (size_t)(n0 + (ci >> 2)) * DD + k0 + (ci & 3) * 8,
                 &sB[wid * 512]);
    }
    __syncthreads();
    bf16x8 af[4], bfr[2];
#pragma unroll
    for (int mi = 0; mi < 4; ++mi)
      af[mi] = *(const bf16x8*)&sA[(wr * 64 + mi * 16 + l16) * 32 + quad * 8];
#pragma unroll
    for (int ni = 0; ni < 2; ++ni)
      bfr[ni] = *(const bf16x8*)&sB[(wc * 32 + ni * 16 + l16) * 32 + quad * 8];
#pragma unroll
    for (int mi = 0; mi < 4; ++mi)
#pragma unroll
      for (int ni = 0; ni < 2; ++ni)
        acc[mi][ni] = __builtin_amdgcn_mfma_f32_16x16x32_bf16(
            af[mi], bfr[ni], acc[mi][ni], 0, 0, 0);
  }
#pragma unroll
  for (int mi = 0; mi < 4; ++mi)
#pragma unroll
    for (int ni = 0; ni < 2; ++ni)
#pragma unroll
      for (int r2 = 0; r2 < 4; ++r2)
        out[(size_t)(m0 + wr * 64 + mi * 16 + quad * 4 + r2) * DD + n0 +
            wc * 32 + ni * 16 + l16] = acc[mi][ni][r2];
}

// ---------------------------------------------------------------------------
extern "C" void kernel_launch(void* const* d_in, const int* in_sizes, int n_in,
                              void* d_out, int out_size, void* d_ws,
                              size_t ws_size, hipStream_t stream) {
  const float* q  = (const float*)d_in[0];
  const float* k  = (const float*)d_in[1];
  const float* v  = (const float*)d_in[2];
  const float* Wq = (const float*)d_in[3];
  const float* Wk = (const float*)d_in[4];
  const float* Wv = (const float*)d_in[5];
  const float* Wo = (const float*)d_in[6];
  const int* mask = (const int*)d_in[7];
  float* out = (float*)d_out;

  // workspace layout (shorts); X aliases qb, vhT aliases kb (dead by then)
  short* ws = (short*)d_ws;
  const size_t NIN = (size_t)BB * SS * DD;  // 4,194,304
  const size_t NWH = (size_t)HH * HD * DD;  // 1,048,576
  short* qb  = ws;        // also X
  short* kb  = ws + NIN;  // also vhT
  short* vb  = ws + 2 * NIN;
  short* WqT = ws + 3 * NIN;
  short* WkT = WqT + NWH;
  short* WvT = WkT + NWH;
  short* WoT = WvT + NWH;
  short* qhp = WoT + (size_t)DD * DD;
  short* khp = qhp + NIN;
  short* vhp = khp + NIN;
  short* Xp  = qb;
  short* vhT = kb;

  prep<<<dim3(13312), 256, 0, stream>>>(q, k, v, Wq, Wk, Wv, Wo, qb, kb, vb,
                                        WqT, WkT, WvT, WoT);
  proj<<<dim3(768), 256, 0, stream>>>(qb, kb, vb, WqT, WkT, WvT, qhp, khp,
                                      vhp);
  vtrans<<<dim3(1024), 256, 0, stream>>>(vhp, vhT);
  attn<<<dim3(2048), 256, 0, stream>>>(qhp, khp, vhT, mask, Xp);
  oproj<<<dim3(32, 16), 256, 0, stream>>>(Xp, WoT, out);
}

// Round 8
// 241.959 us; speedup vs baseline: 1.1912x; 1.0061x over previous
//
#include <hip/hip_runtime.h>
#include <hip/hip_bf16.h>

#define BB 2
#define SS 2048
#define DD 1024
#define HH 16
#define HD 64

typedef __attribute__((ext_vector_type(8))) short bf16x8;
typedef __attribute__((ext_vector_type(4))) float floatx4;

__device__ __forceinline__ short f2bf(float x) {
  __hip_bfloat16 h = __float2bfloat16(x);
  return __builtin_bit_cast(short, h);
}

// branchless RNE fp32->bf16 for values known finite (exp outputs)
__device__ __forceinline__ short f2bf_fast(float x) {
  unsigned u = __float_as_uint(x);
  return (short)((u + 0x7FFFu + ((u >> 16) & 1u)) >> 16);
}

// async global->LDS, 16B per lane; LDS dest is wave-uniform base + lane*16
__device__ __forceinline__ void load_lds16(const void* g, void* l) {
  __builtin_amdgcn_global_load_lds(
      (const __attribute__((address_space(1))) unsigned int*)g,
      (__attribute__((address_space(3))) unsigned int*)l, 16, 0, 0);
}

__device__ __forceinline__ float redsum16(float v) {
  v += __shfl_xor(v, 1, 64);
  v += __shfl_xor(v, 2, 64);
  v += __shfl_xor(v, 4, 64);
  v += __shfl_xor(v, 8, 64);
  return v;
}

// ---------------------------------------------------------------------------
// prep: fused conv_in (q,k,v fp32->bf16) + conv_w (Wq/Wk/Wv transpose) +
// conv_wo (Wo transpose). 1D grid 13312, block 256.
// ---------------------------------------------------------------------------
__global__ __launch_bounds__(256) void prep(
    const float* __restrict__ q, const float* __restrict__ k,
    const float* __restrict__ v, const float* __restrict__ Wq,
    const float* __restrict__ Wk, const float* __restrict__ Wv,
    const float* __restrict__ Wo, short* __restrict__ qo,
    short* __restrict__ ko, short* __restrict__ vo, short* __restrict__ qT,
    short* __restrict__ kT, short* __restrict__ vT, short* __restrict__ WoT) {
  __shared__ short sT[64 * 72];
  const int blk = blockIdx.x;
  if (blk < 12288) {
    const int which = blk >> 12, x = blk & 4095;
    const float* src = which == 0 ? q : which == 1 ? k : v;
    short* dst       = which == 0 ? qo : which == 1 ? ko : vo;
    size_t i = ((size_t)x * 256 + threadIdx.x) * 4;
    float4 f = *(const float4*)(src + i);
    short4 s;
    s.x = f2bf(f.x); s.y = f2bf(f.y); s.z = f2bf(f.z); s.w = f2bf(f.w);
    *(short4*)(dst + i) = s;
    return;
  }
  const int t = threadIdx.x, r = t >> 2, c0 = (t & 3) * 16;
  const float* src;
  short* dst;
  if (blk < 13056) {  // conv_w: W[h][1024][64] -> WT[h*64+e][1024]
    const int b2 = blk - 12288, which = b2 >> 8, rr = b2 & 255;
    const int dtile = rr & 15, h = rr >> 4, d0 = dtile * 64;
    const float* W = which == 0 ? Wq : which == 1 ? Wk : Wv;
    short* WT      = which == 0 ? qT : which == 1 ? kT : vT;
    src = W + ((size_t)h * DD + d0 + r) * HD + c0;
    dst = WT + ((size_t)h * HD + r) * DD + d0 + c0;
  } else {  // conv_wo: Wo[1024][1024] -> WoT[n][k]
    const int b3 = blk - 13056;
    const int k0 = (b3 & 15) * 64, n0 = (b3 >> 4) * 64;
    src = Wo + (size_t)(k0 + r) * DD + n0 + c0;
    dst = WoT + (size_t)(n0 + r) * DD + k0 + c0;
  }
  const float4* s4 = (const float4*)src;
  float4 f0 = s4[0], f1 = s4[1], f2 = s4[2], f3 = s4[3];
  const float ff[16] = {f0.x, f0.y, f0.z, f0.w, f1.x, f1.y, f1.z, f1.w,
                        f2.x, f2.y, f2.z, f2.w, f3.x, f3.y, f3.z, f3.w};
#pragma unroll
  for (int j = 0; j < 16; ++j) sT[r * 72 + c0 + j] = f2bf(ff[j]);
  __syncthreads();
  alignas(16) short tmp[16];
#pragma unroll
  for (int j = 0; j < 16; ++j) tmp[j] = sT[(c0 + j) * 72 + r];
  *(int4*)(dst) = *(const int4*)(tmp);
  *(int4*)(dst + 8) = *(const int4*)(tmp + 8);
}

// ---------------------------------------------------------------------------
// Projection GEMM: ph = x @ W, M=4096, N=1024, K=1024. q/k: plain [m][n]
// store (q pre-scaled 1/8). v: fused transpose epilogue -> vhT[bh][e][s]
// (replaces the old vtrans kernel). 1D grid 768, XCD-decoded so each tile
// lands on the XCD attn will use for those heads (4b + (head_pair>>1)).
// ---------------------------------------------------------------------------
__global__ __launch_bounds__(256) void proj(
    const short* __restrict__ xq, const short* __restrict__ xk,
    const short* __restrict__ xv, const short* __restrict__ WqT,
    const short* __restrict__ WkT, const short* __restrict__ WvT,
    short* __restrict__ qh, short* __restrict__ kh, short* __restrict__ vhT) {
  __shared__ short sA[128 * 32];
  __shared__ short sB[128 * 32];
  __shared__ short sT2[128 * 136];  // v-transpose staging (16B-aligned rows)
  const int xcd = blockIdx.x & 7, tt = blockIdx.x >> 3;
  const int which = tt >> 5;              // 0..2
  const int rest = tt & 31;
  const int j = ((xcd & 3) << 1) | (rest >> 4);   // n-block 0..7
  const int i = ((xcd >> 2) << 4) | (rest & 15);  // m-block 0..31
  const short* X  = which == 0 ? xq : which == 1 ? xk : xv;
  const short* WT = which == 0 ? WqT : which == 1 ? WkT : WvT;
  const int m0 = i * 128, n0 = j * 128;
  const int tid = threadIdx.x, wid = tid >> 6, lane = tid & 63;
  const int quad = lane >> 4, l16 = lane & 15;
  const int wr = wid >> 1, wc = wid & 1;

  floatx4 acc[4][4] = {};
  for (int k0 = 0; k0 < DD; k0 += 32) {
    __syncthreads();
#pragma unroll
    for (int ii = 0; ii < 2; ++ii) {
      const int c = wid * 2 + ii;
      const int ci = c * 64 + lane;
      load_lds16(X + (size_t)(m0 + (ci >> 2)) * DD + k0 + (ci & 3) * 8,
                 &sA[c * 512]);
      load_lds16(WT + (size_t)(n0 + (ci >> 2)) * DD + k0 + (ci & 3) * 8,
                 &sB[c * 512]);
    }
    __syncthreads();
    bf16x8 af[4], bfr[4];
#pragma unroll
    for (int mi = 0; mi < 4; ++mi)
      af[mi] = *(const bf16x8*)&sA[(wr * 64 + mi * 16 + l16) * 32 + quad * 8];
#pragma unroll
    for (int ni = 0; ni < 4; ++ni)
      bfr[ni] = *(const bf16x8*)&sB[(wc * 64 + ni * 16 + l16) * 32 + quad * 8];
#pragma unroll
    for (int mi = 0; mi < 4; ++mi)
#pragma unroll
      for (int ni = 0; ni < 4; ++ni)
        acc[mi][ni] = __builtin_amdgcn_mfma_f32_16x16x32_bf16(
            af[mi], bfr[ni], acc[mi][ni], 0, 0, 0);
  }
  if (which != 2) {
    short* dst = which == 0 ? qh : kh;
    const float scale = (which == 0) ? 0.125f : 1.0f;  // fold 1/sqrt(64) in Q
#pragma unroll
    for (int mi = 0; mi < 4; ++mi)
#pragma unroll
      for (int ni = 0; ni < 4; ++ni)
#pragma unroll
        for (int r2 = 0; r2 < 4; ++r2) {
          const int m = m0 + wr * 64 + mi * 16 + quad * 4 + r2;
          const int n = n0 + wc * 64 + ni * 16 + l16;
          dst[(size_t)m * DD + n] = f2bf(acc[mi][ni][r2] * scale);
        }
  } else {
    // v: transpose 128x128 tile through LDS, store vhT[bh][e][s]
    __syncthreads();  // staging LDS reuse barrier (sT2 is separate, but sync
                      // keeps all waves' acc finalized before the read pass)
#pragma unroll
    for (int mi = 0; mi < 4; ++mi)
#pragma unroll
      for (int ni = 0; ni < 4; ++ni)
#pragma unroll
        for (int r2 = 0; r2 < 4; ++r2) {
          const int ml = wr * 64 + mi * 16 + quad * 4 + r2;  // s-local
          const int nl = wc * 64 + ni * 16 + l16;            // (h,e)-local
          sT2[nl * 136 + ml] = f2bf(acc[mi][ni][r2]);
        }
    __syncthreads();
    const int b = m0 >> 11;
    const int row = tid >> 1, half = tid & 1;  // row = n-local 0..127
    const int h = (n0 + row) >> 6, e = (n0 + row) & 63;
    short* dstp = vhT + ((size_t)(b * HH + h) * HD + e) * SS + (m0 & 2047) +
                  half * 64;
    const short* srcl = &sT2[row * 136 + half * 64];
#pragma unroll
    for (int jj = 0; jj < 8; ++jj)
      *(int4*)(dstp + jj * 8) = *(const int4*)(srcl + jj * 8);
  }
}

// ---------------------------------------------------------------------------
// Flash attention, bf16 MFMA, deferred softmax (t-additive partials), t-split
// across the block's 4 waves (combine = LDS adds). 1D grid 2048, XCD-decoded:
// bh-group {4x..4x+3} on XCD x (heads L2-resident per XCD — FETCH 12.4 MB,
// verified R7). Per-score VALU diet: raw exp -> 2 cndmask (pad), 3-inst RNE
// bf16. X out = flat [b][h][s][e] (reference raw view).
// ---------------------------------------------------------------------------
__global__ __launch_bounds__(256) void attn(
    const short* __restrict__ qh, const short* __restrict__ kh,
    const short* __restrict__ vhT, const int* __restrict__ mask,
    short* __restrict__ X) {
  __shared__ union {
    short sP[4][32 * 72];   // per-wave P tile (main loop), padded stride 72
    float red[2][40 * 64];  // cross-wave reduction slots (after barrier)
  } u;
  const int tid = threadIdx.x, wid = tid >> 6, lane = tid & 63;
  const int quad = lane >> 4, l16 = lane & 15;
  const int xcd = blockIdx.x & 7, slot = blockIdx.x >> 3;  // 0..255
  const int bh = (xcd << 2) | (slot & 3);
  const int strip = 63 - (slot >> 2);  // heavy strips first per XCD
  const int b = bh >> 4, h = bh & 15;
  const int row0 = strip * 32;

  const short* Q  = qh + (size_t)b * SS * DD + h * HD;
  const short* K  = kh + (size_t)b * SS * DD + h * HD;
  const short* Vt = vhT + (size_t)bh * HD * SS;
  const int* mk = mask + b * SS;

  // Q fragments: A-layout, m = l16 (row row0+mi*16+l16), k = ks*32+quad*8
  bf16x8 aq[2][2];
#pragma unroll
  for (int mi = 0; mi < 2; ++mi)
#pragma unroll
    for (int ks = 0; ks < 2; ++ks)
      aq[mi][ks] = *(const bf16x8*)(Q + (size_t)(row0 + mi * 16 + l16) * DD +
                                    ks * 32 + quad * 8);
  bool mrowb[2][4];
#pragma unroll
  for (int mi = 0; mi < 2; ++mi)
#pragma unroll
    for (int r2 = 0; r2 < 4; ++r2)
      mrowb[mi][r2] = mk[row0 + mi * 16 + quad * 4 + r2] != 0;

  floatx4 o[2][4] = {};
  float lacc[2][4];
#pragma unroll
  for (int mi = 0; mi < 2; ++mi)
#pragma unroll
    for (int r2 = 0; r2 < 4; ++r2) lacc[mi][r2] = 0.f;

  const int ntiles = (row0 >> 6) + 1;  // causal extent in 64-col tiles
  for (int tb = wid; tb < ntiles; tb += 4) {
    const int t0 = tb * 64;
    // Issue ALL of this tile's global loads up front (K then V): V-latency
    // overlaps QK + softmax; compiler waits per first use.
    bf16x8 bk[4][2], bv[4][2];
#pragma unroll
    for (int ni = 0; ni < 4; ++ni)
#pragma unroll
      for (int ks = 0; ks < 2; ++ks)
        bk[ni][ks] = *(const bf16x8*)(K + (size_t)(t0 + ni * 16 + l16) * DD +
                                      ks * 32 + quad * 8);
#pragma unroll
    for (int ei = 0; ei < 4; ++ei)
#pragma unroll
      for (int ks = 0; ks < 2; ++ks)
        bv[ei][ks] = *(const bf16x8*)(Vt + (size_t)(ei * 16 + l16) * SS + t0 +
                                      ks * 32 + quad * 8);
    bool mtb[4];
#pragma unroll
    for (int ni = 0; ni < 4; ++ni) mtb[ni] = mk[t0 + ni * 16 + l16] != 0;
    const bool diag = (tb == ntiles - 1);  // wave-uniform

#pragma unroll
    for (int mi = 0; mi < 2; ++mi) {
      floatx4 s[4] = {};
#pragma unroll
      for (int ks = 0; ks < 2; ++ks)
#pragma unroll
        for (int ni = 0; ni < 4; ++ni)
          s[ni] = __builtin_amdgcn_mfma_f32_16x16x32_bf16(
              aq[mi][ks], bk[ni][ks], s[ni], 0, 0, 0);
#pragma unroll
      for (int ni = 0; ni < 4; ++ni)
#pragma unroll
        for (int r2 = 0; r2 < 4; ++r2) {
          // raw exp is safe (|s| bounded); pad cols/rows -> exp(0)=1 exactly
          const float ev = __expf(s[ni][r2]);
          float p = mtb[ni] ? 1.f : ev;         // pad col -> 1
          p = mrowb[mi][r2] ? 1.f : p;          // pad row -> 1
          if (diag) {                            // causal wins over pad
            const int row = row0 + mi * 16 + quad * 4 + r2;
            const int col = t0 + ni * 16 + l16;
            if (col > row) p = 0.f;
          }
          lacc[mi][r2] += p;
          u.sP[wid][(mi * 16 + quad * 4 + r2) * 72 + ni * 16 + l16] =
              f2bf_fast(p);
        }
    }
    // O += P V : P via per-wave LDS round-trip (A-layout); bv already loaded
#pragma unroll
    for (int ks = 0; ks < 2; ++ks) {
      bf16x8 ap[2];
#pragma unroll
      for (int mi = 0; mi < 2; ++mi)
        ap[mi] = *(const bf16x8*)&u.sP[wid][(mi * 16 + l16) * 72 + ks * 32 +
                                            quad * 8];
#pragma unroll
      for (int mi = 0; mi < 2; ++mi)
#pragma unroll
        for (int ei = 0; ei < 4; ++ei)
          o[mi][ei] = __builtin_amdgcn_mfma_f32_16x16x32_bf16(
              ap[mi], bv[ei][ks], o[mi][ei], 0, 0, 0);
    }
  }

  // ---- cross-wave combine: element-major [j][64] slots, pure adds ----
  __syncthreads();  // sP dead from here; red aliases it
  auto dump = [&](float* dst) {
    int j = 0;
#pragma unroll
    for (int mi = 0; mi < 2; ++mi)
#pragma unroll
      for (int ei = 0; ei < 4; ++ei)
#pragma unroll
        for (int r2 = 0; r2 < 4; ++r2) dst[(j++) * 64 + lane] = o[mi][ei][r2];
#pragma unroll
    for (int mi = 0; mi < 2; ++mi)
#pragma unroll
      for (int r2 = 0; r2 < 4; ++r2) dst[(j++) * 64 + lane] = lacc[mi][r2];
  };
  auto accum = [&](const float* srcp) {
    int j = 0;
#pragma unroll
    for (int mi = 0; mi < 2; ++mi)
#pragma unroll
      for (int ei = 0; ei < 4; ++ei)
#pragma unroll
        for (int r2 = 0; r2 < 4; ++r2) o[mi][ei][r2] += srcp[(j++) * 64 + lane];
#pragma unroll
    for (int mi = 0; mi < 2; ++mi)
#pragma unroll
      for (int r2 = 0; r2 < 4; ++r2) lacc[mi][r2] += srcp[(j++) * 64 + lane];
  };
  if (wid == 1) dump(u.red[0]);
  if (wid == 3) dump(u.red[1]);
  __syncthreads();
  if (wid == 0) accum(u.red[0]);
  if (wid == 2) accum(u.red[1]);
  __syncthreads();
  if (wid == 2) dump(u.red[0]);
  __syncthreads();
  if (wid == 0) {
    accum(u.red[0]);
#pragma unroll
    for (int mi = 0; mi < 2; ++mi)
#pragma unroll
      for (int r2 = 0; r2 < 4; ++r2) {
        const float inv = 1.0f / redsum16(lacc[mi][r2]);
        const int srow = row0 + mi * 16 + quad * 4 + r2;
#pragma unroll
        for (int ei = 0; ei < 4; ++ei)
          X[((size_t)bh * SS + srow) * HD + ei * 16 + l16] =
              f2bf(o[mi][ei][r2] * inv);
      }
  }
}

// ---------------------------------------------------------------------------
// out = X[4096,1024] @ Wo, via WoT[n][k]. BM=128 BN=64 BK=32, 256 threads.
// grid (32, 16) = 512 blocks (2/CU). fp32 output.
// ---------------------------------------------------------------------------
__global__ __launch_bounds__(256) void oproj(const short* __restrict__ X,
                                             const short* __restrict__ WoT,
                                             float* __restrict__ out) {
  __shared__ short sA[128 * 32];
  __shared__ short sB[64 * 32];
  const int m0 = blockIdx.x * 128, n0 = blockIdx.y * 64;
  const int tid = threadIdx.x, wid = tid >> 6, lane = tid & 63;
  const int quad = lane >> 4, l16 = lane & 15;
  const int wr = wid >> 1, wc = wid & 1;

  floatx4 acc[4][2] = {};
  for (int k0 = 0; k0 < DD; k0 += 32) {
    __syncthreads();
#pragma unroll
    for (int i = 0; i < 2; ++i) {
      const int c = wid * 2 + i;
      const int ci = c * 64 + lane;
      load_lds16(X + (size_t)(m0 + (ci >> 2)) * DD + k0 + (ci & 3) * 8,
                 &sA[c * 512]);
    }
    {
      const int ci = wid * 64 + lane;
      load_lds16(WoT + (size_t)(n0 + (ci >> 2)) * DD + k0 + (ci & 3) * 8,
                 &sB[wid * 512]);
    }
    __syncthreads();
    bf16x8 af[4], bfr[2];
#pragma unroll
    for (int mi = 0; mi < 4; ++mi)
      af[mi] = *(const bf16x8*)&sA[(wr * 64 + mi * 16 + l16) * 32 + quad * 8];
#pragma unroll
    for (int ni = 0; ni < 2; ++ni)
      bfr[ni] = *(const bf16x8*)&sB[(wc * 32 + ni * 16 + l16) * 32 + quad * 8];
#pragma unroll
    for (int mi = 0; mi < 4; ++mi)
#pragma unroll
      for (int ni = 0; ni < 2; ++ni)
        acc[mi][ni] = __builtin_amdgcn_mfma_f32_16x16x32_bf16(
            af[mi], bfr[ni], acc[mi][ni], 0, 0, 0);
  }
#pragma unroll
  for (int mi = 0; mi < 4; ++mi)
#pragma unroll
    for (int ni = 0; ni < 2; ++ni)
#pragma unroll
      for (int r2 = 0; r2 < 4; ++r2)
        out[(size_t)(m0 + wr * 64 + mi * 16 + quad * 4 + r2) * DD + n0 +
            wc * 32 + ni * 16 + l16] = acc[mi][ni][r2];
}

// ---------------------------------------------------------------------------
extern "C" void kernel_launch(void* const* d_in, const int* in_sizes, int n_in,
                              void* d_out, int out_size, void* d_ws,
                              size_t ws_size, hipStream_t stream) {
  const float* q  = (const float*)d_in[0];
  const float* k  = (const float*)d_in[1];
  const float* v  = (const float*)d_in[2];
  const float* Wq = (const float*)d_in[3];
  const float* Wk = (const float*)d_in[4];
  const float* Wv = (const float*)d_in[5];
  const float* Wo = (const float*)d_in[6];
  const int* mask = (const int*)d_in[7];
  float* out = (float*)d_out;

  // workspace layout (shorts); X aliases qb (dead after proj). vhT has its
  // OWN region (kb is still live while proj writes vhT).
  short* ws = (short*)d_ws;
  const size_t NIN = (size_t)BB * SS * DD;  // 4,194,304
  const size_t NWH = (size_t)HH * HD * DD;  // 1,048,576
  short* qb  = ws;        // also X
  short* kb  = ws + NIN;
  short* vb  = ws + 2 * NIN;
  short* WqT = ws + 3 * NIN;
  short* WkT = WqT + NWH;
  short* WvT = WkT + NWH;
  short* WoT = WvT + NWH;
  short* qhp = WoT + (size_t)DD * DD;
  short* khp = qhp + NIN;
  short* vhT = khp + NIN;
  short* Xp  = qb;

  prep<<<dim3(13312), 256, 0, stream>>>(q, k, v, Wq, Wk, Wv, Wo, qb, kb, vb,
                                        WqT, WkT, WvT, WoT);
  proj<<<dim3(768), 256, 0, stream>>>(qb, kb, vb, WqT, WkT, WvT, qhp, khp,
                                      vhT);
  attn<<<dim3(2048), 256, 0, stream>>>(qhp, khp, vhT, mask, Xp);
  oproj<<<dim3(32, 16), 256, 0, stream>>>(Xp, WoT, out);
}